// Round 2
// baseline (9820.182 us; speedup 1.0000x reference)
//
#include <hip/hip_runtime.h>
#include <math.h>

// ESBN: encoder (conv x3 + linear) + 64-step LSTM/memory scan. fp32 throughout.

__device__ __forceinline__ float sigm(float x) { return 1.0f / (1.0f + expf(-x)); }

// ---------------------------------------------------------------------------
// Encoder: one block per sample (T*B = 16384 blocks), 192 threads.
// LDS: c1 [32][15][16-pad] = 7680 f ; buf = img(3072 f) then c2(2304 f).
// conv3 partials / c3 / z-partials reuse the c1 region after conv2.
// Weights are read from global (L1-resident walk patterns).
// ---------------------------------------------------------------------------
#define ENT 192
__global__ __launch_bounds__(ENT) void encoder_kernel(
    const float* __restrict__ images,
    const float* __restrict__ w1, const float* __restrict__ b1,
    const float* __restrict__ w2, const float* __restrict__ b2,
    const float* __restrict__ w3, const float* __restrict__ b3,
    const float* __restrict__ ew, const float* __restrict__ eb,
    float* __restrict__ z_all)
{
  __shared__ __align__(16) float c1[7680];
  __shared__ __align__(16) float buf[3072];
  const int bid = blockIdx.x;
  const int tid = threadIdx.x;

  // load image (3,32,32)
  for (int i = tid; i < 3072; i += ENT) buf[i] = images[(size_t)bid * 3072 + i];
  __syncthreads();

  // ---- conv1: 3->32, k4 s2, out 15x15, ReLU. tile = 4oc x 5pos. 360 slots.
  for (int s = tid; s < 360; s += ENT) {
    const int ocg  = s & 7;          // 8 groups of 4 oc
    const int pg   = s >> 3;         // 0..44
    const int row  = pg / 3;
    const int colg = pg - row * 3;
    const int ox0  = colg * 5;
    float acc[4][5];
    #pragma unroll
    for (int o = 0; o < 4; ++o) {
      const float bb = b1[ocg * 4 + o];
      #pragma unroll
      for (int p = 0; p < 5; ++p) acc[o][p] = bb;
    }
    #pragma unroll
    for (int ic = 0; ic < 3; ++ic) {
      #pragma unroll
      for (int ky = 0; ky < 4; ++ky) {
        const int y = 2 * row + ky;
        const float* ib = &buf[ic * 1024 + y * 32 + 2 * ox0];
        float v[12];
        #pragma unroll
        for (int i = 0; i < 6; ++i) { float2 t2 = *(const float2*)(ib + 2 * i); v[2*i] = t2.x; v[2*i+1] = t2.y; }
        #pragma unroll
        for (int o = 0; o < 4; ++o) {
          const float4 w = *(const float4*)(w1 + (ocg * 4 + o) * 48 + ic * 16 + ky * 4);
          #pragma unroll
          for (int p = 0; p < 5; ++p)
            acc[o][p] += w.x * v[2*p] + w.y * v[2*p+1] + w.z * v[2*p+2] + w.w * v[2*p+3];
        }
      }
    }
    #pragma unroll
    for (int o = 0; o < 4; ++o)
      #pragma unroll
      for (int p = 0; p < 5; ++p)
        c1[(ocg * 4 + o) * 240 + row * 16 + ox0 + p] = fmaxf(acc[o][p], 0.0f);
  }
  __syncthreads();

  // ---- conv2: 32->64, k4 s2, out 6x6, ReLU. tile = 4oc x 3pos. 192 slots (exact).
  {
    const int ocg = tid & 15;        // 16 groups of 4 oc
    const int pg  = tid >> 4;        // 0..11
    const int row = pg >> 1;
    const int ox0 = (pg & 1) * 3;
    float acc[4][3];
    #pragma unroll
    for (int o = 0; o < 4; ++o) {
      const float bb = b2[ocg * 4 + o];
      acc[o][0] = bb; acc[o][1] = bb; acc[o][2] = bb;
    }
    for (int ic = 0; ic < 32; ++ic) {
      #pragma unroll
      for (int ky = 0; ky < 4; ++ky) {
        const int y = 2 * row + ky;
        const float* ib = &c1[ic * 240 + y * 16 + 2 * ox0];
        float v[8];
        #pragma unroll
        for (int i = 0; i < 4; ++i) { float2 t2 = *(const float2*)(ib + 2 * i); v[2*i] = t2.x; v[2*i+1] = t2.y; }
        #pragma unroll
        for (int o = 0; o < 4; ++o) {
          const float4 w = *(const float4*)(w2 + (ocg * 4 + o) * 512 + ic * 16 + ky * 4);
          #pragma unroll
          for (int p = 0; p < 3; ++p)
            acc[o][p] += w.x * v[2*p] + w.y * v[2*p+1] + w.z * v[2*p+2] + w.w * v[2*p+3];
        }
      }
    }
    // imgs in buf are dead (conv1 barrier passed); store c2 into buf.
    #pragma unroll
    for (int o = 0; o < 4; ++o)
      #pragma unroll
      for (int p = 0; p < 3; ++p)
        buf[(ocg * 4 + o) * 36 + row * 6 + ox0 + p] = fmaxf(acc[o][p], 0.0f);
  }
  __syncthreads();

  // ---- conv3: 64->64, k4 s2, out 2x2, NO ReLU.
  // thread = (4oc-group x 12 k-chunks) over 256 (ic,ky) iterations.
  {
    const int ocg = tid & 15;
    const int kc  = tid >> 4;        // 0..11
    const int it0 = (kc < 4) ? kc * 22 : 88 + (kc - 4) * 21;
    const int itn = (kc < 4) ? 22 : 21;
    float acc[4][4];
    #pragma unroll
    for (int o = 0; o < 4; ++o) { acc[o][0]=0.f; acc[o][1]=0.f; acc[o][2]=0.f; acc[o][3]=0.f; }
    for (int it = it0; it < it0 + itn; ++it) {
      const int ic = it >> 2;        // 0..63
      const int ky = it & 3;
      float v[2][6];
      #pragma unroll
      for (int oy = 0; oy < 2; ++oy) {
        const float* ib = &buf[ic * 36 + (2 * oy + ky) * 6];
        #pragma unroll
        for (int i = 0; i < 3; ++i) { float2 t2 = *(const float2*)(ib + 2 * i); v[oy][2*i] = t2.x; v[oy][2*i+1] = t2.y; }
      }
      #pragma unroll
      for (int o = 0; o < 4; ++o) {
        const float4 w = *(const float4*)(w3 + (ocg * 4 + o) * 1024 + ic * 16 + ky * 4);
        #pragma unroll
        for (int p = 0; p < 4; ++p) {
          const int oy = p >> 1, ox = p & 1;
          acc[o][p] += w.x * v[oy][2*ox] + w.y * v[oy][2*ox+1] + w.z * v[oy][2*ox+2] + w.w * v[oy][2*ox+3];
        }
      }
    }
    // partials into c1[0..3072): psum[(oc*4+pos)*12 + kc]
    #pragma unroll
    for (int o = 0; o < 4; ++o)
      #pragma unroll
      for (int p = 0; p < 4; ++p)
        c1[((ocg * 4 + o) * 4 + p) * 12 + kc] = acc[o][p];
  }
  __syncthreads();

  // reduce conv3 partials -> c3 (flatten order c*4 + h*2 + w), + bias, no ReLU
  for (int o = tid; o < 256; o += ENT) {
    float s = b3[o >> 2];
    #pragma unroll
    for (int kc = 0; kc < 12; ++kc) s += c1[o * 12 + kc];
    c1[3072 + o] = s;
  }
  __syncthreads();

  // linear 256 -> 64 : thread = (d 0..63, kchunk 0..2)
  {
    const int d  = tid & 63;
    const int kc = tid >> 6;
    const int k0 = (kc * 256) / 3, k1 = ((kc + 1) * 256) / 3;
    float s = 0.0f;
    for (int k = k0; k < k1; ++k) s += ew[d * 256 + k] * c1[3072 + k];
    c1[3328 + kc * 64 + d] = s;
  }
  __syncthreads();
  if (tid < 64) {
    z_all[(size_t)bid * 64 + tid] = eb[tid] + c1[3328 + tid] + c1[3392 + tid] + c1[3456 + tid];
  }
}

// ---------------------------------------------------------------------------
// Kernel A (per step): gates = [kx|h] @ [w_ih|w_hh]^T + biases, fused LSTM
// elementwise. Grid (16 b-tiles, 16 j-tiles), 256 threads.
// Thread = 2 b x 1 j x 4 gates. X staged in LDS; W walked from global (L1).
// ---------------------------------------------------------------------------
#define XS 584   // 65 kx + 7 pad + 512 h (h starts at 72, 16B aligned)
__global__ __launch_bounds__(256) void lstm_gates_kernel(
    const float* __restrict__ KX, const float* __restrict__ Hprev,
    float* __restrict__ Hout, float* __restrict__ C,
    const float* __restrict__ w_ih, const float* __restrict__ w_hh,
    const float* __restrict__ b_ih, const float* __restrict__ b_hh)
{
  __shared__ __align__(16) float Xs[16 * XS];
  const int b0  = blockIdx.x * 16;
  const int tid = threadIdx.x;
  const int tb  = tid >> 5;                 // 0..7
  const int jj  = blockIdx.y * 32 + (tid & 31);

  for (int i = tid; i < 16 * 65; i += 256) {
    const int bb = i / 65; const int k = i - bb * 65;
    Xs[bb * XS + k] = KX[(b0 + bb) * 65 + k];
  }
  for (int i = tid; i < 16 * 512; i += 256) {
    const int bb = i >> 9; const int k = i & 511;
    Xs[bb * XS + 72 + k] = Hprev[(size_t)(b0 + bb) * 512 + k];
  }
  __syncthreads();

  float a00, a01, a02, a03, a10, a11, a12, a13;
  {
    const float bi0 = b_ih[jj]        + b_hh[jj];
    const float bi1 = b_ih[512 + jj]  + b_hh[512 + jj];
    const float bi2 = b_ih[1024 + jj] + b_hh[1024 + jj];
    const float bi3 = b_ih[1536 + jj] + b_hh[1536 + jj];
    a00 = bi0; a01 = bi1; a02 = bi2; a03 = bi3;
    a10 = bi0; a11 = bi1; a12 = bi2; a13 = bi3;
  }
  // kx part (K = 65)
  {
    const float* r0 = w_ih + (size_t)jj * 65;
    const float* r1 = w_ih + (size_t)(512 + jj) * 65;
    const float* r2 = w_ih + (size_t)(1024 + jj) * 65;
    const float* r3 = w_ih + (size_t)(1536 + jj) * 65;
    const float* x0p = &Xs[tb * XS];
    const float* x1p = &Xs[(tb + 8) * XS];
    for (int k = 0; k < 65; ++k) {
      const float x0 = x0p[k], x1 = x1p[k];
      const float u0 = r0[k], u1 = r1[k], u2 = r2[k], u3 = r3[k];
      a00 += x0 * u0; a01 += x0 * u1; a02 += x0 * u2; a03 += x0 * u3;
      a10 += x1 * u0; a11 += x1 * u1; a12 += x1 * u2; a13 += x1 * u3;
    }
  }
  // h part (K = 512), float4-vectorized
  {
    const float* r0 = w_hh + (size_t)jj * 512;
    const float* r1 = w_hh + (size_t)(512 + jj) * 512;
    const float* r2 = w_hh + (size_t)(1024 + jj) * 512;
    const float* r3 = w_hh + (size_t)(1536 + jj) * 512;
    const float* x0p = &Xs[tb * XS + 72];
    const float* x1p = &Xs[(tb + 8) * XS + 72];
    #pragma unroll 2
    for (int k = 0; k < 512; k += 4) {
      const float4 x0 = *(const float4*)(x0p + k);
      const float4 x1 = *(const float4*)(x1p + k);
      float4 w;
      w = *(const float4*)(r0 + k);
      a00 += x0.x*w.x + x0.y*w.y + x0.z*w.z + x0.w*w.w;
      a10 += x1.x*w.x + x1.y*w.y + x1.z*w.z + x1.w*w.w;
      w = *(const float4*)(r1 + k);
      a01 += x0.x*w.x + x0.y*w.y + x0.z*w.z + x0.w*w.w;
      a11 += x1.x*w.x + x1.y*w.y + x1.z*w.z + x1.w*w.w;
      w = *(const float4*)(r2 + k);
      a02 += x0.x*w.x + x0.y*w.y + x0.z*w.z + x0.w*w.w;
      a12 += x1.x*w.x + x1.y*w.y + x1.z*w.z + x1.w*w.w;
      w = *(const float4*)(r3 + k);
      a03 += x0.x*w.x + x0.y*w.y + x0.z*w.z + x0.w*w.w;
      a13 += x1.x*w.x + x1.y*w.y + x1.z*w.z + x1.w*w.w;
    }
  }
  // LSTM elementwise (torch gate order i,f,g,o)
  {
    const size_t idx = (size_t)(b0 + tb) * 512 + jj;
    const float cold = C[idx];
    const float c2v  = sigm(a01) * cold + sigm(a00) * tanhf(a02);
    C[idx] = c2v;
    Hout[idx] = sigm(a03) * tanhf(c2v);
  }
  {
    const size_t idx = (size_t)(b0 + tb + 8) * 512 + jj;
    const float cold = C[idx];
    const float c2v  = sigm(a11) * cold + sigm(a10) * tanhf(a12);
    C[idx] = c2v;
    Hout[idx] = sigm(a13) * tanhf(c2v);
  }
}

// ---------------------------------------------------------------------------
// Kernel B (per step): y/g/kw dots, masked softmax over z-Gram row, memory
// read -> kx_{t+1}. One block per batch element, 256 threads.
// MkT layout: [b][d][n] (d-major) so the attention read is contiguous in n.
// ---------------------------------------------------------------------------
__global__ __launch_bounds__(256) void step_kernel(
    const int t,
    const float* __restrict__ H, const float* __restrict__ z_all,
    float* __restrict__ MkT, float* __restrict__ KX, float* __restrict__ out,
    const float* __restrict__ out_w, const float* __restrict__ out_b,
    const float* __restrict__ gate_w, const float* __restrict__ gate_b,
    const float* __restrict__ key_w, const float* __restrict__ key_b,
    const float* __restrict__ conf_w, const float* __restrict__ conf_b)
{
  const int b   = blockIdx.x;
  const int tid = threadIdx.x;
  __shared__ __align__(16) float hs[512];
  __shared__ __align__(16) float zs[64];
  __shared__ __align__(16) float wks[64];
  __shared__ __align__(16) float psum[256];
  __shared__ float sgv, kx64v;

  for (int i = tid; i < 512; i += 256) hs[i] = H[(size_t)b * 512 + i];
  if (tid < 64) zs[tid] = z_all[((size_t)t * 256 + b) * 64 + tid];
  __syncthreads();

  // 69 dot products of length 512: kw[0..63], y[64..67], g[68]
  const int wv = tid >> 6, lane = tid & 63;
  for (int d = wv; d < 69; d += 4) {
    const float* row = (d < 64) ? (key_w + (size_t)d * 512)
                     : (d < 68) ? (out_w + (size_t)(d - 64) * 512)
                                : gate_w;
    float a = 0.0f;
    #pragma unroll
    for (int k = 0; k < 8; ++k) a += hs[lane + k * 64] * row[lane + k * 64];
    #pragma unroll
    for (int m = 32; m > 0; m >>= 1) a += __shfl_xor(a, m);
    if (lane == 0) {
      if (d < 64)      MkT[(size_t)b * 4096 + d * 64 + t] = a + key_b[d];
      else if (d < 68) out[(size_t)t * 1024 + b * 4 + (d - 64)] = a + out_b[d - 64];
      else             sgv = sigm(a + gate_b[0]);
    }
  }
  __syncthreads();

  if (t == 0) {
    if (tid < 65) KX[b * 65 + tid] = 0.0f;
    return;
  }

  // masked softmax over sim_n = z_t . z_n (n < t), plus ck column
  if (tid < 64) {
    const int n = tid;
    const float* zr = z_all + ((size_t)n * 256 + b) * 64;
    float sim = 0.0f;
    #pragma unroll
    for (int i = 0; i < 16; ++i) {
      const float4 a4 = *(const float4*)(zs + 4 * i);
      const float4 b4 = *(const float4*)(zr + 4 * i);
      sim += a4.x * b4.x + a4.y * b4.y + a4.z * b4.z + a4.w * b4.w;
    }
    const bool valid = (n < t);
    float mx = valid ? sim : -3.0e38f;
    #pragma unroll
    for (int m = 32; m > 0; m >>= 1) mx = fmaxf(mx, __shfl_xor(mx, m));
    const float p = valid ? expf(sim - mx) : 0.0f;
    float sum = p;
    #pragma unroll
    for (int m = 32; m > 0; m >>= 1) sum += __shfl_xor(sum, m);
    const float wk = p / sum;
    wks[n] = wk;
    float kc = wk * sigm(sim * conf_w[0] + conf_b[0]);
    #pragma unroll
    for (int m = 32; m > 0; m >>= 1) kc += __shfl_xor(kc, m);
    if (n == 0) kx64v = kc;
  }
  __syncthreads();

  // kx[d] = sg * sum_n wk[n] * MkT[b][d][n]   (wk[n>=t] == 0)
  {
    const int d = tid >> 2, q = tid & 3;
    const float* mr = MkT + (size_t)b * 4096 + d * 64 + q * 16;
    const float* wr = wks + q * 16;
    float a = 0.0f;
    #pragma unroll
    for (int i = 0; i < 4; ++i) {
      const float4 m4 = *(const float4*)(mr + 4 * i);
      const float4 w4 = *(const float4*)(wr + 4 * i);
      a += m4.x * w4.x + m4.y * w4.y + m4.z * w4.z + m4.w * w4.w;
    }
    psum[tid] = a;
  }
  __syncthreads();
  if (tid < 64) {
    KX[b * 65 + tid] = sgv * (psum[tid * 4] + psum[tid * 4 + 1] + psum[tid * 4 + 2] + psum[tid * 4 + 3]);
  } else if (tid == 64) {
    KX[b * 65 + 64] = sgv * kx64v;
  }
}

// ---------------------------------------------------------------------------
extern "C" void kernel_launch(void* const* d_in, const int* in_sizes, int n_in,
                              void* d_out, int out_size, void* d_ws, size_t ws_size,
                              hipStream_t stream) {
  const float* images = (const float*)d_in[0];
  const float* w1     = (const float*)d_in[1];
  const float* b1     = (const float*)d_in[2];
  const float* w2     = (const float*)d_in[3];
  const float* b2     = (const float*)d_in[4];
  const float* w3     = (const float*)d_in[5];
  const float* b3     = (const float*)d_in[6];
  const float* ew     = (const float*)d_in[7];
  const float* eb     = (const float*)d_in[8];
  const float* w_ih   = (const float*)d_in[9];
  const float* w_hh   = (const float*)d_in[10];
  const float* b_ih   = (const float*)d_in[11];
  const float* b_hh   = (const float*)d_in[12];
  const float* out_w  = (const float*)d_in[13];
  const float* out_b  = (const float*)d_in[14];
  const float* gate_w = (const float*)d_in[15];
  const float* gate_b = (const float*)d_in[16];
  const float* key_w  = (const float*)d_in[17];
  const float* key_b  = (const float*)d_in[18];
  const float* conf_w = (const float*)d_in[19];
  const float* conf_b = (const float*)d_in[20];
  float* out = (float*)d_out;
  float* ws  = (float*)d_ws;

  float* z_all = ws;                 // 16384*64      = 1,048,576 f
  float* MkT   = ws + 1048576;       // 256*64*64     = 1,048,576 f
  float* H0    = ws + 2097152;       // 256*512       =   131,072 f
  float* H1    = ws + 2228224;       //                  131,072 f
  float* C     = ws + 2359296;       //                  131,072 f
  float* KX    = ws + 2490368;       // 256*65        =    16,640 f

  hipMemsetAsync(H0,  0, 131072 * sizeof(float), stream);
  hipMemsetAsync(C,   0, 131072 * sizeof(float), stream);
  hipMemsetAsync(KX,  0, 16640  * sizeof(float), stream);
  hipMemsetAsync(MkT, 0, 1048576 * sizeof(float), stream);

  encoder_kernel<<<16384, ENT, 0, stream>>>(images, w1, b1, w2, b2, w3, b3, ew, eb, z_all);

  for (int t = 0; t < 64; ++t) {
    const float* Hp = (t & 1) ? H1 : H0;
    float*       Hn = (t & 1) ? H0 : H1;
    lstm_gates_kernel<<<dim3(16, 16), 256, 0, stream>>>(KX, Hp, Hn, C, w_ih, w_hh, b_ih, b_hh);
    step_kernel<<<256, 256, 0, stream>>>(t, Hn, z_all, MkT, KX, out,
                                         out_w, out_b, gate_w, gate_b,
                                         key_w, key_b, conf_w, conf_b);
  }
}

// Round 3
// 7481.065 us; speedup vs baseline: 1.3127x; 1.3127x over previous
//
#include <hip/hip_runtime.h>
#include <math.h>

// ESBN: encoder (conv x3 + linear) + 64-step LSTM/memory scan. fp32.
// R3: transposed (lane-coalesced) weights via prep kernel; LDS bank-conflict
// padding; XC=[kx|h] concat buffer for a coalesced gates GEMM.

__device__ __forceinline__ float sigm(float x) { return 1.0f / (1.0f + expf(-x)); }

// ---------------------------------------------------------------------------
// prep: build transposed weights in ws.
//   WT   [580][2048] : rows 0..64 = w_ih^T, 65..576 = w_hh^T, 577..579 = 0
//   bsum [2048]      : b_ih + b_hh
//   w1T  [48][32], w2T [512][64], w3T [1024][64] : r = ic*16+ky*4+kx
//   ewT  [256][64]
// ---------------------------------------------------------------------------
#define PREP_N (1187840 + 2048 + 1536 + 32768 + 65536 + 16384)
__global__ __launch_bounds__(256) void prep_kernel(
    const float* __restrict__ w_ih, const float* __restrict__ w_hh,
    const float* __restrict__ b_ih, const float* __restrict__ b_hh,
    const float* __restrict__ w1, const float* __restrict__ w2,
    const float* __restrict__ w3, const float* __restrict__ ew,
    float* __restrict__ WT, float* __restrict__ bsum,
    float* __restrict__ w1T, float* __restrict__ w2T,
    float* __restrict__ w3T, float* __restrict__ ewT)
{
  int i = blockIdx.x * 256 + threadIdx.x;
  if (i < 1187840) {                       // WT
    const int r = i >> 11, c = i & 2047;
    float v;
    if (r < 65)       v = w_ih[(size_t)c * 65 + r];
    else if (r < 577) v = w_hh[(size_t)c * 512 + (r - 65)];
    else              v = 0.0f;
    WT[i] = v; return;
  }
  i -= 1187840;
  if (i < 2048) { bsum[i] = b_ih[i] + b_hh[i]; return; }
  i -= 2048;
  if (i < 1536) { const int r = i >> 5, oc = i & 31; w1T[i] = w1[oc * 48 + r]; return; }
  i -= 1536;
  if (i < 32768) { const int r = i >> 6, oc = i & 63; w2T[i] = w2[oc * 512 + r]; return; }
  i -= 32768;
  if (i < 65536) { const int r = i >> 6, oc = i & 63; w3T[i] = w3[oc * 1024 + r]; return; }
  i -= 65536;
  if (i < 16384) { const int k = i >> 6, d = i & 63; ewT[i] = ew[d * 256 + k]; return; }
}

// ---------------------------------------------------------------------------
// Encoder: one block per sample (16384 blocks), 192 threads.
// c1 [32][242] (7744 f) ; buf: img (3072 f) -> c2 [64][38] (2432 f).
// conv3 psum [3][4][64] at c1[0..780); c3 at c1[1024..1280);
// linear partials at c1[1536..1728).
// ---------------------------------------------------------------------------
#define ENT 192
__global__ __launch_bounds__(ENT) void encoder_kernel(
    const float* __restrict__ images,
    const float* __restrict__ w1T, const float* __restrict__ b1,
    const float* __restrict__ w2T, const float* __restrict__ b2,
    const float* __restrict__ w3T, const float* __restrict__ b3,
    const float* __restrict__ ewT, const float* __restrict__ eb,
    float* __restrict__ z_all)
{
  __shared__ __align__(16) float c1[7744];
  __shared__ __align__(16) float buf[3072];
  const int bid = blockIdx.x;
  const int tid = threadIdx.x;

  // load image (3,32,32) vectorized
  {
    const float4* src = (const float4*)(images + (size_t)bid * 3072);
    float4* dst = (float4*)buf;
    for (int i = tid; i < 768; i += ENT) dst[i] = src[i];
  }
  __syncthreads();

  // ---- conv1: 3->32, k4 s2, out 15x15, ReLU. tile = 4oc x 5pos. 360 slots.
  for (int s = tid; s < 360; s += ENT) {
    const int ocg  = s & 7;
    const int pg   = s >> 3;
    const int row  = pg / 3;
    const int colg = pg - row * 3;
    const int ox0  = colg * 5;
    float acc[4][5];
    #pragma unroll
    for (int o = 0; o < 4; ++o) {
      const float bb = b1[ocg * 4 + o];
      #pragma unroll
      for (int p = 0; p < 5; ++p) acc[o][p] = bb;
    }
    #pragma unroll
    for (int ic = 0; ic < 3; ++ic) {
      #pragma unroll
      for (int ky = 0; ky < 4; ++ky) {
        const int y = 2 * row + ky;
        const float* ib = &buf[ic * 1024 + y * 32 + 2 * ox0];
        float v[12];
        #pragma unroll
        for (int i = 0; i < 6; ++i) { float2 t2 = *(const float2*)(ib + 2 * i); v[2*i] = t2.x; v[2*i+1] = t2.y; }
        float w_[4][4];
        #pragma unroll
        for (int kx = 0; kx < 4; ++kx)
          *(float4*)&w_[kx][0] = *(const float4*)(w1T + (ic * 16 + ky * 4 + kx) * 32 + ocg * 4);
        #pragma unroll
        for (int o = 0; o < 4; ++o)
          #pragma unroll
          for (int p = 0; p < 5; ++p)
            acc[o][p] += w_[0][o] * v[2*p] + w_[1][o] * v[2*p+1] + w_[2][o] * v[2*p+2] + w_[3][o] * v[2*p+3];
      }
    }
    #pragma unroll
    for (int o = 0; o < 4; ++o)
      #pragma unroll
      for (int p = 0; p < 5; ++p)
        c1[(ocg * 4 + o) * 242 + row * 16 + ox0 + p] = fmaxf(acc[o][p], 0.0f);
  }
  __syncthreads();

  // ---- conv2: 32->64, k4 s2, out 6x6, ReLU. tile = 4oc x 3pos. 192 slots.
  {
    const int ocg = tid & 15;
    const int pg  = tid >> 4;
    const int row = pg >> 1;
    const int ox0 = (pg & 1) * 3;
    float acc[4][3];
    #pragma unroll
    for (int o = 0; o < 4; ++o) {
      const float bb = b2[ocg * 4 + o];
      acc[o][0] = bb; acc[o][1] = bb; acc[o][2] = bb;
    }
    for (int ic = 0; ic < 32; ++ic) {
      #pragma unroll
      for (int ky = 0; ky < 4; ++ky) {
        const int y = 2 * row + ky;
        const float* ib = &c1[ic * 242 + y * 16 + 2 * ox0];
        float v[8];
        #pragma unroll
        for (int i = 0; i < 4; ++i) { float2 t2 = *(const float2*)(ib + 2 * i); v[2*i] = t2.x; v[2*i+1] = t2.y; }
        float w_[4][4];
        #pragma unroll
        for (int kx = 0; kx < 4; ++kx)
          *(float4*)&w_[kx][0] = *(const float4*)(w2T + (ic * 16 + ky * 4 + kx) * 64 + ocg * 4);
        #pragma unroll
        for (int o = 0; o < 4; ++o)
          #pragma unroll
          for (int p = 0; p < 3; ++p)
            acc[o][p] += w_[0][o] * v[2*p] + w_[1][o] * v[2*p+1] + w_[2][o] * v[2*p+2] + w_[3][o] * v[2*p+3];
      }
    }
    __syncthreads();  // all conv2 reads of c1 done before conv3 overwrites c1
    #pragma unroll
    for (int o = 0; o < 4; ++o)
      #pragma unroll
      for (int p = 0; p < 3; ++p)
        buf[(ocg * 4 + o) * 38 + row * 6 + ox0 + p] = fmaxf(acc[o][p], 0.0f);
  }
  __syncthreads();

  // ---- conv3: 64->64, k4 s2, out 2x2, NO ReLU. thread = oc(64) x kc(3).
  {
    const int oc = tid & 63;
    const int kc = tid >> 6;                       // 0..2
    const int k0 = (kc * 256) / 3, k1 = ((kc + 1) * 256) / 3;
    float acc[4] = {0.f, 0.f, 0.f, 0.f};
    for (int it = k0; it < k1; ++it) {
      const int ic = it >> 2;
      const int ky = it & 3;
      float v[2][6];
      #pragma unroll
      for (int oy = 0; oy < 2; ++oy) {
        const float* ib = &buf[ic * 38 + (2 * oy + ky) * 6];
        #pragma unroll
        for (int i = 0; i < 3; ++i) { float2 t2 = *(const float2*)(ib + 2 * i); v[oy][2*i] = t2.x; v[oy][2*i+1] = t2.y; }
      }
      float w_[4];
      #pragma unroll
      for (int kx = 0; kx < 4; ++kx) w_[kx] = w3T[(ic * 16 + ky * 4 + kx) * 64 + oc];
      #pragma unroll
      for (int p = 0; p < 4; ++p) {
        const int oy = p >> 1, ox = p & 1;
        acc[p] += w_[0] * v[oy][2*ox] + w_[1] * v[oy][2*ox+1] + w_[2] * v[oy][2*ox+2] + w_[3] * v[oy][2*ox+3];
      }
    }
    // psum[kc][p][oc] at c1[0..780)
    #pragma unroll
    for (int p = 0; p < 4; ++p) c1[kc * 260 + p * 64 + oc] = acc[p];
  }
  __syncthreads();

  // reduce psum -> c3 (flatten c*4 + h*2 + w) + bias, at c1[1024..1280)
  for (int o = tid; o < 256; o += ENT) {
    const int oc = o >> 2, p = o & 3;
    c1[1024 + o] = b3[oc] + c1[p * 64 + oc] + c1[260 + p * 64 + oc] + c1[520 + p * 64 + oc];
  }
  __syncthreads();

  // linear 256 -> 64 : thread = (d 0..63, kchunk 0..2)
  {
    const int d  = tid & 63;
    const int kc = tid >> 6;
    const int k0 = (kc * 256) / 3, k1 = ((kc + 1) * 256) / 3;
    float s = 0.0f;
    for (int k = k0; k < k1; ++k) s += ewT[k * 64 + d] * c1[1024 + k];
    c1[1536 + kc * 64 + d] = s;
  }
  __syncthreads();
  if (tid < 64) {
    z_all[(size_t)bid * 64 + tid] = eb[tid] + c1[1536 + tid] + c1[1600 + tid] + c1[1664 + tid];
  }
}

// ---------------------------------------------------------------------------
// gates: [256 b][580 k] XC  @  WT [580][2048]  (+bsum) -> LSTM elementwise.
// grid (16 btiles, 16 jtiles) x 256 thr; thread = 1b x 2j x 4gates.
// WT reads coalesced (lanes = consecutive j); XC reads 16-lane broadcast.
// ---------------------------------------------------------------------------
__global__ __launch_bounds__(256) void lstm_gates_kernel(
    const float* __restrict__ XC, const float* __restrict__ WT,
    const float* __restrict__ bsum, float* __restrict__ H, float* __restrict__ C)
{
  const int tid = threadIdx.x;
  const int b   = blockIdx.x * 16 + (tid >> 4);
  const int j   = blockIdx.y * 32 + (tid & 15) * 2;
  const float* xr = XC + (size_t)b * 580;
  const float* wp = WT + j;
  float acc[4][2] = {{0.f,0.f},{0.f,0.f},{0.f,0.f},{0.f,0.f}};
  for (int k = 0; k < 580; k += 4) {
    const float4 xv = *(const float4*)(xr + k);
    const float xk[4] = {xv.x, xv.y, xv.z, xv.w};
    #pragma unroll
    for (int kk = 0; kk < 4; ++kk) {
      const float* wr = wp + (size_t)(k + kk) * 2048;
      #pragma unroll
      for (int g = 0; g < 4; ++g) {
        const float2 wv = *(const float2*)(wr + g * 512);
        acc[g][0] += xk[kk] * wv.x;
        acc[g][1] += xk[kk] * wv.y;
      }
    }
  }
  #pragma unroll
  for (int jj = 0; jj < 2; ++jj) {
    const float iv = acc[0][jj] + bsum[j + jj];
    const float fv = acc[1][jj] + bsum[512 + j + jj];
    const float gv = acc[2][jj] + bsum[1024 + j + jj];
    const float ov = acc[3][jj] + bsum[1536 + j + jj];
    const size_t idx = (size_t)b * 512 + j + jj;
    const float c2v = sigm(fv) * C[idx] + sigm(iv) * tanhf(gv);
    C[idx] = c2v;
    H[idx] = sigm(ov) * tanhf(c2v);
  }
}

// ---------------------------------------------------------------------------
// step: y/g/kw dots, masked softmax over z-Gram row, memory read -> XC_{t+1}.
// One block per batch element. Writes XC = [kx_{t+1} | h_t].
// ---------------------------------------------------------------------------
__global__ __launch_bounds__(256) void step_kernel(
    const int t,
    const float* __restrict__ H, const float* __restrict__ z_all,
    float* __restrict__ MkT, float* __restrict__ XC, float* __restrict__ out,
    const float* __restrict__ out_w, const float* __restrict__ out_b,
    const float* __restrict__ gate_w, const float* __restrict__ gate_b,
    const float* __restrict__ key_w, const float* __restrict__ key_b,
    const float* __restrict__ conf_w, const float* __restrict__ conf_b)
{
  const int b   = blockIdx.x;
  const int tid = threadIdx.x;
  __shared__ __align__(16) float hs[512];
  __shared__ __align__(16) float zs[64];
  __shared__ __align__(16) float wks[64];
  __shared__ __align__(16) float psum[256];
  __shared__ float sgv, kx64v;

  for (int i = tid; i < 512; i += 256) {
    const float hv = H[(size_t)b * 512 + i];
    hs[i] = hv;
    XC[(size_t)b * 580 + 65 + i] = hv;          // h part of next-step input
  }
  if (tid < 64) zs[tid] = z_all[((size_t)t * 256 + b) * 64 + tid];
  __syncthreads();

  // 69 dot products of length 512: kw[0..63], y[64..67], g[68]
  const int wv = tid >> 6, lane = tid & 63;
  for (int d = wv; d < 69; d += 4) {
    const float* row = (d < 64) ? (key_w + (size_t)d * 512)
                     : (d < 68) ? (out_w + (size_t)(d - 64) * 512)
                                : gate_w;
    float a = 0.0f;
    #pragma unroll
    for (int k = 0; k < 8; ++k) a += hs[lane + k * 64] * row[lane + k * 64];
    #pragma unroll
    for (int m = 32; m > 0; m >>= 1) a += __shfl_xor(a, m);
    if (lane == 0) {
      if (d < 64)      MkT[(size_t)b * 4096 + d * 64 + t] = a + key_b[d];
      else if (d < 68) out[(size_t)t * 1024 + b * 4 + (d - 64)] = a + out_b[d - 64];
      else             sgv = sigm(a + gate_b[0]);
    }
  }
  __syncthreads();

  if (t == 0) {
    if (tid < 65) XC[(size_t)b * 580 + tid] = 0.0f;   // kx_1 = 0
    return;
  }

  // masked softmax over sim_n = z_t . z_n (n < t), plus ck column
  if (tid < 64) {
    const int n = tid;
    const float* zr = z_all + ((size_t)n * 256 + b) * 64;
    float sim = 0.0f;
    #pragma unroll
    for (int i = 0; i < 16; ++i) {
      const float4 a4 = *(const float4*)(zs + 4 * i);
      const float4 b4 = *(const float4*)(zr + 4 * i);
      sim += a4.x * b4.x + a4.y * b4.y + a4.z * b4.z + a4.w * b4.w;
    }
    const bool valid = (n < t);
    float mx = valid ? sim : -3.0e38f;
    #pragma unroll
    for (int m = 32; m > 0; m >>= 1) mx = fmaxf(mx, __shfl_xor(mx, m));
    const float p = valid ? expf(sim - mx) : 0.0f;
    float sum = p;
    #pragma unroll
    for (int m = 32; m > 0; m >>= 1) sum += __shfl_xor(sum, m);
    const float wk = p / sum;
    wks[n] = wk;
    float kc = wk * sigm(sim * conf_w[0] + conf_b[0]);
    #pragma unroll
    for (int m = 32; m > 0; m >>= 1) kc += __shfl_xor(kc, m);
    if (n == 0) kx64v = kc;
  }
  __syncthreads();

  // kx[d] = sg * sum_n wk[n] * MkT[b][d][n]   (wk[n>=t] == 0)
  {
    const int d = tid >> 2, q = tid & 3;
    const float* mr = MkT + (size_t)b * 4096 + d * 64 + q * 16;
    const float* wr = wks + q * 16;
    float a = 0.0f;
    #pragma unroll
    for (int i = 0; i < 4; ++i) {
      const float4 m4 = *(const float4*)(mr + 4 * i);
      const float4 w4 = *(const float4*)(wr + 4 * i);
      a += m4.x * w4.x + m4.y * w4.y + m4.z * w4.z + m4.w * w4.w;
    }
    psum[tid] = a;
  }
  __syncthreads();
  if (tid < 64) {
    XC[(size_t)b * 580 + tid] = sgv * (psum[tid * 4] + psum[tid * 4 + 1] + psum[tid * 4 + 2] + psum[tid * 4 + 3]);
  } else if (tid == 64) {
    XC[(size_t)b * 580 + 64] = sgv * kx64v;
  }
}

// ---------------------------------------------------------------------------
extern "C" void kernel_launch(void* const* d_in, const int* in_sizes, int n_in,
                              void* d_out, int out_size, void* d_ws, size_t ws_size,
                              hipStream_t stream) {
  const float* images = (const float*)d_in[0];
  const float* w1     = (const float*)d_in[1];
  const float* b1     = (const float*)d_in[2];
  const float* w2     = (const float*)d_in[3];
  const float* b2     = (const float*)d_in[4];
  const float* w3     = (const float*)d_in[5];
  const float* b3     = (const float*)d_in[6];
  const float* ew     = (const float*)d_in[7];
  const float* eb     = (const float*)d_in[8];
  const float* w_ih   = (const float*)d_in[9];
  const float* w_hh   = (const float*)d_in[10];
  const float* b_ih   = (const float*)d_in[11];
  const float* b_hh   = (const float*)d_in[12];
  const float* out_w  = (const float*)d_in[13];
  const float* out_b  = (const float*)d_in[14];
  const float* gate_w = (const float*)d_in[15];
  const float* gate_b = (const float*)d_in[16];
  const float* key_w  = (const float*)d_in[17];
  const float* key_b  = (const float*)d_in[18];
  const float* conf_w = (const float*)d_in[19];
  const float* conf_b = (const float*)d_in[20];
  float* out = (float*)d_out;
  float* ws  = (float*)d_ws;

  // ws layout (floats)
  float* WT    = ws;                          // 580*2048 = 1,187,840
  float* bsum  = ws + 1187840;                // 2048
  float* w1T   = ws + 1189888;                // 1536
  float* w2T   = ws + 1191424;                // 32768
  float* w3T   = ws + 1224192;                // 65536
  float* ewT   = ws + 1289728;                // 16384
  float* z_all = ws + 1306112;                // 16384*64 = 1,048,576
  float* MkT   = ws + 2354688;                // 256*64*64 = 1,048,576
  float* H     = ws + 3403264;                // 256*512 = 131,072
  float* C     = ws + 3534336;                // 131,072
  float* XC    = ws + 3665408;                // 256*580 = 148,480
  // total 3,813,888 floats = 15.3 MB

  hipMemsetAsync(C,  0, 131072 * sizeof(float), stream);
  hipMemsetAsync(XC, 0, 148480 * sizeof(float), stream);

  prep_kernel<<<(PREP_N + 255) / 256, 256, 0, stream>>>(
      w_ih, w_hh, b_ih, b_hh, w1, w2, w3, ew, WT, bsum, w1T, w2T, w3T, ewT);

  encoder_kernel<<<16384, ENT, 0, stream>>>(images, w1T, b1, w2T, b2, w3T, b3, ewT, eb, z_all);

  for (int t = 0; t < 64; ++t) {
    lstm_gates_kernel<<<dim3(16, 16), 256, 0, stream>>>(XC, WT, bsum, H, C);
    step_kernel<<<256, 256, 0, stream>>>(t, H, z_all, MkT, XC, out,
                                         out_w, out_b, gate_w, gate_b,
                                         key_w, key_b, conf_w, conf_b);
  }
}

// Round 4
// 4132.234 us; speedup vs baseline: 2.3765x; 1.8104x over previous
//
#include <hip/hip_runtime.h>
#include <math.h>

// ESBN: encoder (conv x3 + linear) + 64-step LSTM/memory scan. fp32.
// R4: K-split high-occupancy gates GEMM (XCD-resident WT slices), LSTM
// elementwise fused into step kernel, one-time z-Gram precompute.

__device__ __forceinline__ float sigm(float x) { return 1.0f / (1.0f + expf(-x)); }

// ---------------------------------------------------------------------------
// prep: build transposed weights in ws.
//   WT   [580][2048] : rows 0..64 = w_ih^T, 65..576 = w_hh^T, 577..579 = 0
//   bsum [2048]      : b_ih + b_hh
//   w1T  [48][32], w2T [512][64], w3T [1024][64] : r = ic*16+ky*4+kx
//   ewT  [256][64]
// ---------------------------------------------------------------------------
#define PREP_N (1187840 + 2048 + 1536 + 32768 + 65536 + 16384)
__global__ __launch_bounds__(256) void prep_kernel(
    const float* __restrict__ w_ih, const float* __restrict__ w_hh,
    const float* __restrict__ b_ih, const float* __restrict__ b_hh,
    const float* __restrict__ w1, const float* __restrict__ w2,
    const float* __restrict__ w3, const float* __restrict__ ew,
    float* __restrict__ WT, float* __restrict__ bsum,
    float* __restrict__ w1T, float* __restrict__ w2T,
    float* __restrict__ w3T, float* __restrict__ ewT)
{
  int i = blockIdx.x * 256 + threadIdx.x;
  if (i < 1187840) {                       // WT
    const int r = i >> 11, c = i & 2047;
    float v;
    if (r < 65)       v = w_ih[(size_t)c * 65 + r];
    else if (r < 577) v = w_hh[(size_t)c * 512 + (r - 65)];
    else              v = 0.0f;
    WT[i] = v; return;
  }
  i -= 1187840;
  if (i < 2048) { bsum[i] = b_ih[i] + b_hh[i]; return; }
  i -= 2048;
  if (i < 1536) { const int r = i >> 5, oc = i & 31; w1T[i] = w1[oc * 48 + r]; return; }
  i -= 1536;
  if (i < 32768) { const int r = i >> 6, oc = i & 63; w2T[i] = w2[oc * 512 + r]; return; }
  i -= 32768;
  if (i < 65536) { const int r = i >> 6, oc = i & 63; w3T[i] = w3[oc * 1024 + r]; return; }
  i -= 65536;
  if (i < 16384) { const int k = i >> 6, d = i & 63; ewT[i] = ew[d * 256 + k]; return; }
}

// ---------------------------------------------------------------------------
// Encoder: one block per sample (16384 blocks), 192 threads. (unchanged R3)
// ---------------------------------------------------------------------------
#define ENT 192
__global__ __launch_bounds__(ENT) void encoder_kernel(
    const float* __restrict__ images,
    const float* __restrict__ w1T, const float* __restrict__ b1,
    const float* __restrict__ w2T, const float* __restrict__ b2,
    const float* __restrict__ w3T, const float* __restrict__ b3,
    const float* __restrict__ ewT, const float* __restrict__ eb,
    float* __restrict__ z_all)
{
  __shared__ __align__(16) float c1[7744];
  __shared__ __align__(16) float buf[3072];
  const int bid = blockIdx.x;
  const int tid = threadIdx.x;

  {
    const float4* src = (const float4*)(images + (size_t)bid * 3072);
    float4* dst = (float4*)buf;
    for (int i = tid; i < 768; i += ENT) dst[i] = src[i];
  }
  __syncthreads();

  // ---- conv1: 3->32, k4 s2, out 15x15, ReLU. tile = 4oc x 5pos. 360 slots.
  for (int s = tid; s < 360; s += ENT) {
    const int ocg  = s & 7;
    const int pg   = s >> 3;
    const int row  = pg / 3;
    const int colg = pg - row * 3;
    const int ox0  = colg * 5;
    float acc[4][5];
    #pragma unroll
    for (int o = 0; o < 4; ++o) {
      const float bb = b1[ocg * 4 + o];
      #pragma unroll
      for (int p = 0; p < 5; ++p) acc[o][p] = bb;
    }
    #pragma unroll
    for (int ic = 0; ic < 3; ++ic) {
      #pragma unroll
      for (int ky = 0; ky < 4; ++ky) {
        const int y = 2 * row + ky;
        const float* ib = &buf[ic * 1024 + y * 32 + 2 * ox0];
        float v[12];
        #pragma unroll
        for (int i = 0; i < 6; ++i) { float2 t2 = *(const float2*)(ib + 2 * i); v[2*i] = t2.x; v[2*i+1] = t2.y; }
        float w_[4][4];
        #pragma unroll
        for (int kx = 0; kx < 4; ++kx)
          *(float4*)&w_[kx][0] = *(const float4*)(w1T + (ic * 16 + ky * 4 + kx) * 32 + ocg * 4);
        #pragma unroll
        for (int o = 0; o < 4; ++o)
          #pragma unroll
          for (int p = 0; p < 5; ++p)
            acc[o][p] += w_[0][o] * v[2*p] + w_[1][o] * v[2*p+1] + w_[2][o] * v[2*p+2] + w_[3][o] * v[2*p+3];
      }
    }
    #pragma unroll
    for (int o = 0; o < 4; ++o)
      #pragma unroll
      for (int p = 0; p < 5; ++p)
        c1[(ocg * 4 + o) * 242 + row * 16 + ox0 + p] = fmaxf(acc[o][p], 0.0f);
  }
  __syncthreads();

  // ---- conv2: 32->64, k4 s2, out 6x6, ReLU. tile = 4oc x 3pos. 192 slots.
  {
    const int ocg = tid & 15;
    const int pg  = tid >> 4;
    const int row = pg >> 1;
    const int ox0 = (pg & 1) * 3;
    float acc[4][3];
    #pragma unroll
    for (int o = 0; o < 4; ++o) {
      const float bb = b2[ocg * 4 + o];
      acc[o][0] = bb; acc[o][1] = bb; acc[o][2] = bb;
    }
    for (int ic = 0; ic < 32; ++ic) {
      #pragma unroll
      for (int ky = 0; ky < 4; ++ky) {
        const int y = 2 * row + ky;
        const float* ib = &c1[ic * 242 + y * 16 + 2 * ox0];
        float v[8];
        #pragma unroll
        for (int i = 0; i < 4; ++i) { float2 t2 = *(const float2*)(ib + 2 * i); v[2*i] = t2.x; v[2*i+1] = t2.y; }
        float w_[4][4];
        #pragma unroll
        for (int kx = 0; kx < 4; ++kx)
          *(float4*)&w_[kx][0] = *(const float4*)(w2T + (ic * 16 + ky * 4 + kx) * 64 + ocg * 4);
        #pragma unroll
        for (int o = 0; o < 4; ++o)
          #pragma unroll
          for (int p = 0; p < 3; ++p)
            acc[o][p] += w_[0][o] * v[2*p] + w_[1][o] * v[2*p+1] + w_[2][o] * v[2*p+2] + w_[3][o] * v[2*p+3];
      }
    }
    __syncthreads();
    #pragma unroll
    for (int o = 0; o < 4; ++o)
      #pragma unroll
      for (int p = 0; p < 3; ++p)
        buf[(ocg * 4 + o) * 38 + row * 6 + ox0 + p] = fmaxf(acc[o][p], 0.0f);
  }
  __syncthreads();

  // ---- conv3: 64->64, k4 s2, out 2x2, NO ReLU. thread = oc(64) x kc(3).
  {
    const int oc = tid & 63;
    const int kc = tid >> 6;
    const int k0 = (kc * 256) / 3, k1 = ((kc + 1) * 256) / 3;
    float acc[4] = {0.f, 0.f, 0.f, 0.f};
    for (int it = k0; it < k1; ++it) {
      const int ic = it >> 2;
      const int ky = it & 3;
      float v[2][6];
      #pragma unroll
      for (int oy = 0; oy < 2; ++oy) {
        const float* ib = &buf[ic * 38 + (2 * oy + ky) * 6];
        #pragma unroll
        for (int i = 0; i < 3; ++i) { float2 t2 = *(const float2*)(ib + 2 * i); v[oy][2*i] = t2.x; v[oy][2*i+1] = t2.y; }
      }
      float w_[4];
      #pragma unroll
      for (int kx = 0; kx < 4; ++kx) w_[kx] = w3T[(ic * 16 + ky * 4 + kx) * 64 + oc];
      #pragma unroll
      for (int p = 0; p < 4; ++p) {
        const int oy = p >> 1, ox = p & 1;
        acc[p] += w_[0] * v[oy][2*ox] + w_[1] * v[oy][2*ox+1] + w_[2] * v[oy][2*ox+2] + w_[3] * v[oy][2*ox+3];
      }
    }
    #pragma unroll
    for (int p = 0; p < 4; ++p) c1[kc * 260 + p * 64 + oc] = acc[p];
  }
  __syncthreads();

  for (int o = tid; o < 256; o += ENT) {
    const int oc = o >> 2, p = o & 3;
    c1[1024 + o] = b3[oc] + c1[p * 64 + oc] + c1[260 + p * 64 + oc] + c1[520 + p * 64 + oc];
  }
  __syncthreads();

  {
    const int d  = tid & 63;
    const int kc = tid >> 6;
    const int k0 = (kc * 256) / 3, k1 = ((kc + 1) * 256) / 3;
    float s = 0.0f;
    for (int k = k0; k < k1; ++k) s += ewT[k * 64 + d] * c1[1024 + k];
    c1[1536 + kc * 64 + d] = s;
  }
  __syncthreads();
  if (tid < 64) {
    z_all[(size_t)bid * 64 + tid] = eb[tid] + c1[1536 + tid] + c1[1600 + tid] + c1[1664 + tid];
  }
}

// ---------------------------------------------------------------------------
// z-Gram: z_gram[b][t][n] = z_t . z_n  (one-time, after encoder)
// ---------------------------------------------------------------------------
__global__ __launch_bounds__(256) void gram_kernel(
    const float* __restrict__ z_all, float* __restrict__ z_gram)
{
  const int b = blockIdx.x;
  const int tid = threadIdx.x;
  __shared__ float zsb[64 * 65];
  for (int i = tid; i < 4096; i += 256) {
    const int tt = i >> 6, d = i & 63;
    zsb[tt * 65 + d] = z_all[((size_t)tt * 256 + b) * 64 + d];
  }
  __syncthreads();
  const int n = tid & 63, tg = tid >> 6;
  for (int tt = tg; tt < 64; tt += 4) {
    float s = 0.0f;
    #pragma unroll
    for (int d = 0; d < 64; ++d) s += zsb[tt * 65 + d] * zsb[n * 65 + d];
    z_gram[((size_t)b * 64 + tt) * 64 + n] = s;
  }
}

// ---------------------------------------------------------------------------
// gates partial GEMM: Gp[kc][256][2048] = XC[:,k0:k1] @ WT[k0:k1,:]
// grid (8*kcn, 16 btiles) x 256 thr; thread = 4b x 4j, float4 WT loads.
// Packing blockIdx.x = jt*kcn+kc keeps all btiles of one WT slice on one XCD
// (linear ids differ by gridDim.x=8*kcn, a multiple of 8).
// ---------------------------------------------------------------------------
__global__ __launch_bounds__(256) void gates_partial_kernel(
    const float* __restrict__ XC, const float* __restrict__ WT,
    float* __restrict__ Gp, const int kchunk, const int klog)
{
  extern __shared__ float xs[];          // [16][kchunk]
  const int bx  = blockIdx.x;
  const int kc  = bx & ((1 << klog) - 1);
  const int jt  = bx >> klog;
  const int tid = threadIdx.x;
  const int tj  = tid & 63, tb = tid >> 6;
  const int k0  = kc * kchunk;
  const int b0  = blockIdx.y * 16;
  const int j0  = jt * 256 + tj * 4;

  const int NS = 16 * kchunk;
  for (int i = tid; i < NS; i += 256) {
    const int b = i / kchunk, k = i - b * kchunk;
    xs[b * kchunk + k] = XC[(size_t)(b0 + b) * 580 + k0 + k];
  }
  __syncthreads();

  float acc[4][4];
  #pragma unroll
  for (int bb = 0; bb < 4; ++bb)
    #pragma unroll
    for (int jj = 0; jj < 4; ++jj) acc[bb][jj] = 0.0f;

  const float* wp = WT + (size_t)k0 * 2048 + j0;
  const float* xp = xs + tb * 4 * kchunk;
  #pragma unroll 4
  for (int k = 0; k < kchunk; ++k) {
    const float4 w = *(const float4*)(wp + (size_t)k * 2048);
    #pragma unroll
    for (int bb = 0; bb < 4; ++bb) {
      const float xv = xp[bb * kchunk + k];
      acc[bb][0] += xv * w.x; acc[bb][1] += xv * w.y;
      acc[bb][2] += xv * w.z; acc[bb][3] += xv * w.w;
    }
  }
  #pragma unroll
  for (int bb = 0; bb < 4; ++bb) {
    float4 r; r.x = acc[bb][0]; r.y = acc[bb][1]; r.z = acc[bb][2]; r.w = acc[bb][3];
    *(float4*)(Gp + ((size_t)kc * 256 + b0 + tb * 4 + bb) * 2048 + j0) = r;
  }
}

// ---------------------------------------------------------------------------
// fused step: (1) LSTM elementwise from Gp partials -> h (LDS) / C / XC-h,
// (2) 69 dots, (3) masked softmax from z_gram row, (4) memory read -> XC-kx.
// One block per batch element.
// ---------------------------------------------------------------------------
__global__ __launch_bounds__(256) void step_fused_kernel(
    const int t, const int kcn,
    const float* __restrict__ Gp, const float* __restrict__ bsum,
    float* __restrict__ C, const float* __restrict__ z_gram,
    float* __restrict__ MkT, float* __restrict__ XC, float* __restrict__ out,
    const float* __restrict__ out_w, const float* __restrict__ out_b,
    const float* __restrict__ gate_w, const float* __restrict__ gate_b,
    const float* __restrict__ key_w, const float* __restrict__ key_b,
    const float* __restrict__ conf_w, const float* __restrict__ conf_b)
{
  const int b   = blockIdx.x;
  const int tid = threadIdx.x;
  __shared__ __align__(16) float hs[512];
  __shared__ __align__(16) float wks[64];
  __shared__ __align__(16) float psum[256];
  __shared__ float sgv, kx64v;

  // --- phase 1: LSTM elementwise for this b
  for (int jj = tid; jj < 512; jj += 256) {
    float gv[4];
    #pragma unroll
    for (int g = 0; g < 4; ++g) {
      float s = bsum[g * 512 + jj];
      for (int kc = 0; kc < kcn; ++kc)
        s += Gp[((size_t)kc * 256 + b) * 2048 + g * 512 + jj];
      gv[g] = s;
    }
    const size_t cidx = (size_t)b * 512 + jj;
    const float c2v = sigm(gv[1]) * C[cidx] + sigm(gv[0]) * tanhf(gv[2]);
    C[cidx] = c2v;
    const float h = sigm(gv[3]) * tanhf(c2v);
    hs[jj] = h;
    XC[(size_t)b * 580 + 65 + jj] = h;
  }
  __syncthreads();

  // --- phase 2: 69 dot products of length 512: kw[0..63], y[64..67], g[68]
  const int wv = tid >> 6, lane = tid & 63;
  for (int d = wv; d < 69; d += 4) {
    const float* row = (d < 64) ? (key_w + (size_t)d * 512)
                     : (d < 68) ? (out_w + (size_t)(d - 64) * 512)
                                : gate_w;
    float a = 0.0f;
    #pragma unroll
    for (int k = 0; k < 8; ++k) a += hs[lane + k * 64] * row[lane + k * 64];
    #pragma unroll
    for (int m = 32; m > 0; m >>= 1) a += __shfl_xor(a, m);
    if (lane == 0) {
      if (d < 64)      MkT[(size_t)b * 4096 + d * 64 + t] = a + key_b[d];
      else if (d < 68) out[(size_t)t * 1024 + b * 4 + (d - 64)] = a + out_b[d - 64];
      else             sgv = sigm(a + gate_b[0]);
    }
  }
  __syncthreads();

  if (t == 0) {
    if (tid < 65) XC[(size_t)b * 580 + tid] = 0.0f;   // kx_1 = 0
    return;
  }

  // --- phase 3: masked softmax over sim_n (n < t), plus ck column
  if (tid < 64) {
    const int n = tid;
    const float sim = z_gram[((size_t)b * 64 + t) * 64 + n];
    const bool valid = (n < t);
    float mx = valid ? sim : -3.0e38f;
    #pragma unroll
    for (int m = 32; m > 0; m >>= 1) mx = fmaxf(mx, __shfl_xor(mx, m));
    const float p = valid ? expf(sim - mx) : 0.0f;
    float sum = p;
    #pragma unroll
    for (int m = 32; m > 0; m >>= 1) sum += __shfl_xor(sum, m);
    const float wk = p / sum;
    wks[n] = wk;
    float kc = wk * sigm(sim * conf_w[0] + conf_b[0]);
    #pragma unroll
    for (int m = 32; m > 0; m >>= 1) kc += __shfl_xor(kc, m);
    if (n == 0) kx64v = kc;
  }
  __syncthreads();

  // --- phase 4: kx[d] = sg * sum_n wk[n] * MkT[b][d][n]
  {
    const int d = tid >> 2, q = tid & 3;
    const float* mr = MkT + (size_t)b * 4096 + d * 64 + q * 16;
    const float* wr = wks + q * 16;
    float a = 0.0f;
    #pragma unroll
    for (int i = 0; i < 4; ++i) {
      const float4 m4 = *(const float4*)(mr + 4 * i);
      const float4 w4 = *(const float4*)(wr + 4 * i);
      a += m4.x * w4.x + m4.y * w4.y + m4.z * w4.z + m4.w * w4.w;
    }
    psum[tid] = a;
  }
  __syncthreads();
  if (tid < 64) {
    XC[(size_t)b * 580 + tid] = sgv * (psum[tid * 4] + psum[tid * 4 + 1] + psum[tid * 4 + 2] + psum[tid * 4 + 3]);
  } else if (tid == 64) {
    XC[(size_t)b * 580 + 64] = sgv * kx64v;
  }
}

// ---------------------------------------------------------------------------
extern "C" void kernel_launch(void* const* d_in, const int* in_sizes, int n_in,
                              void* d_out, int out_size, void* d_ws, size_t ws_size,
                              hipStream_t stream) {
  const float* images = (const float*)d_in[0];
  const float* w1     = (const float*)d_in[1];
  const float* b1     = (const float*)d_in[2];
  const float* w2     = (const float*)d_in[3];
  const float* b2     = (const float*)d_in[4];
  const float* w3     = (const float*)d_in[5];
  const float* b3     = (const float*)d_in[6];
  const float* ew     = (const float*)d_in[7];
  const float* eb     = (const float*)d_in[8];
  const float* w_ih   = (const float*)d_in[9];
  const float* w_hh   = (const float*)d_in[10];
  const float* b_ih   = (const float*)d_in[11];
  const float* b_hh   = (const float*)d_in[12];
  const float* out_w  = (const float*)d_in[13];
  const float* out_b  = (const float*)d_in[14];
  const float* gate_w = (const float*)d_in[15];
  const float* gate_b = (const float*)d_in[16];
  const float* key_w  = (const float*)d_in[17];
  const float* key_b  = (const float*)d_in[18];
  const float* conf_w = (const float*)d_in[19];
  const float* conf_b = (const float*)d_in[20];
  float* out = (float*)d_out;
  float* ws  = (float*)d_ws;

  // ws layout (floats)
  float* WT     = ws;                  // 1,187,840
  float* bsum   = ws + 1187840;        // 2,048
  float* w1T    = ws + 1189888;        // 1,536
  float* w2T    = ws + 1191424;        // 32,768
  float* w3T    = ws + 1224192;        // 65,536
  float* ewT    = ws + 1289728;        // 16,384
  float* z_all  = ws + 1306112;        // 1,048,576
  float* MkT    = ws + 2354688;        // 1,048,576
  float* C      = ws + 3403264;        // 131,072
  float* XC     = ws + 3534336;        // 148,480
  float* z_gram = ws + 3682816;        // 1,048,576
  float* Gp     = ws + 4731392;        // kcn * 524,288

  // pick K-split from available scratch (base 4,731,392 f + kcn*524,288 f)
  int kcn = 4, klog = 2, kchunk = 145;
  if (ws_size < (4731392ull + 4ull * 524288ull) * 4ull) { kcn = 2; klog = 1; kchunk = 290; }
  if (ws_size < (4731392ull + 2ull * 524288ull) * 4ull) { kcn = 1; klog = 0; kchunk = 580; }

  hipMemsetAsync(C,  0, 131072 * sizeof(float), stream);
  hipMemsetAsync(XC, 0, 148480 * sizeof(float), stream);

  prep_kernel<<<(PREP_N + 255) / 256, 256, 0, stream>>>(
      w_ih, w_hh, b_ih, b_hh, w1, w2, w3, ew, WT, bsum, w1T, w2T, w3T, ewT);

  encoder_kernel<<<16384, ENT, 0, stream>>>(images, w1T, b1, w2T, b2, w3T, b3, ewT, eb, z_all);

  gram_kernel<<<256, 256, 0, stream>>>(z_all, z_gram);

  const size_t lds_stage = (size_t)16 * kchunk * sizeof(float);
  for (int t = 0; t < 64; ++t) {
    gates_partial_kernel<<<dim3(8 * kcn, 16), 256, lds_stage, stream>>>(
        XC, WT, Gp, kchunk, klog);
    step_fused_kernel<<<256, 256, 0, stream>>>(
        t, kcn, Gp, bsum, C, z_gram, MkT, XC, out,
        out_w, out_b, gate_w, gate_b, key_w, key_b, conf_w, conf_b);
  }
}